// Round 1
// 253.738 us; speedup vs baseline: 1.0047x; 1.0047x over previous
//
#include <hip/hip_runtime.h>

#define N_NODES 50000
#define NFEAT   512
#define NHID    128
#define N_EDGES 800000
#define LN_EPS  1e-5f

#define GEMM_ROWS   32
#define GEMM_BLOCKS ((N_NODES + GEMM_ROWS - 1) / GEMM_ROWS)   // 1563
#define DEG_BLOCKS  (N_EDGES / 256)                           // 3125
#define NB_SCAN     ((N_NODES + 1023) / 1024)                 // 49

typedef __attribute__((ext_vector_type(8))) short bf16x8;
typedef __attribute__((ext_vector_type(4))) float fx4;

__device__ __forceinline__ unsigned short f2bf(float f) {
    union { float f; unsigned u; } v; v.f = f;
    unsigned r = v.u + 0x7FFF + ((v.u >> 16) & 1);   // RNE
    return (unsigned short)(r >> 16);
}

// unpack 2 bf16 packed in a uint -> 2 floats (bf16 = top half of fp32)
__device__ __forceinline__ void bf2x(unsigned u, float& lo, float& hi) {
    union { unsigned u; float f; } a, b;
    a.u = u << 16;
    b.u = u & 0xFFFF0000u;
    lo = a.f; hi = b.f;
}

// ---------------- prep: zero degree arrays + W -> bf16 fragment order ----------------
// grid 64x256. All threads zero 2*DEG_BYTES; blocks 0..31 also transpose W.
__global__ __launch_bounds__(256) void prep_kernel(
    const float* __restrict__ W, unsigned short* __restrict__ wf,
    int4* __restrict__ zero_ptr)
{
    int t = blockIdx.x * 256 + threadIdx.x;      // 0..16383
#pragma unroll
    for (int i = t; i < 25088; i += 16384)       // 2*200704/16
        zero_ptr[i] = make_int4(0, 0, 0, 0);

    if (blockIdx.x < 32) {
        int lane = t & 63;
        int frag = t >> 6;                       // 0..127 = kc*8 + tt
        int kc = frag >> 3, tt = frag & 7;
        int n  = tt * 16 + (lane & 15);
        int k0 = kc * 32 + (lane >> 4) * 8;
        unsigned short v[8];
#pragma unroll
        for (int j = 0; j < 8; j++)
            v[j] = f2bf(W[(size_t)(k0 + j) * NHID + n]);
        *(bf16x8*)(wf + (size_t)t * 8) = *(bf16x8*)v;
    }
}

// ---------------- fused: GEMM (even blocks of first span) + degree (rest) ----------------
// GEMM writes x_bf16 = bf16(h @ W); out_norm applied later in aggregate.
// LDS granules XOR-swizzled: G' = q*16 + (rr ^ (q | ((kc&1)<<2))) -> 2-way max on writes.
__global__ __launch_bounds__(256) void fused_gemm_degree(
    const float* __restrict__ h, const unsigned short* __restrict__ wf,
    unsigned short* __restrict__ x,
    const int* __restrict__ src, const int* __restrict__ dst,
    int* __restrict__ out_deg, int* __restrict__ in_deg,
    int* __restrict__ edge_pos)
{
    __shared__ __align__(16) unsigned short afrag_lds[2][16 * 64 * 8];   // 32 KB

    const int tid = threadIdx.x;
    const int B = blockIdx.x;
    bool isDeg; int id;
    if (B < 2 * GEMM_BLOCKS) { isDeg = (B & 1); id = B >> 1; }
    else                     { isDeg = true;    id = B - GEMM_BLOCKS; }

    if (isDeg) {
        int e = id * 256 + tid;
        int s = src[e];
        int d = dst[e];
        int pos = atomicAdd(&in_deg[d], 1);
        atomicAdd(&out_deg[s], 1);
        edge_pos[e] = pos;
        return;
    }

    // ---- GEMM: 32 rows per block ----
    const int row0 = id * GEMM_ROWS;

    // staging: two batches of 8 float4 loads held in registers -> deep MLP
#pragma unroll
    for (int half = 0; half < 2; half++) {
        float4 v[8];
#pragma unroll
        for (int it = 0; it < 8; it++) {
            int i = tid + (half * 8 + it) * 256;   // float4 index, 0..4095
            int r = i >> 7;                        // row 0..31
            int grow = row0 + r;
            if (grow > N_NODES - 1) grow = N_NODES - 1;
            v[it] = ((const float4*)h)[(size_t)grow * 128 + (i & 127)];
        }
#pragma unroll
        for (int it = 0; it < 8; it++) {
            int i = tid + (half * 8 + it) * 256;
            int r  = i >> 7;
            int g  = r >> 4;
            int rr = r & 15;
            int k0 = (i & 127) << 2;
            int kc = k0 >> 5;
            int q  = (k0 >> 3) & 3;
            int j  = k0 & 7;
            int gp = q * 16 + (rr ^ (q | ((kc & 1) << 2)));   // swizzled granule
            unsigned long long pk =
                (unsigned long long)f2bf(v[it].x)
              | ((unsigned long long)f2bf(v[it].y) << 16)
              | ((unsigned long long)f2bf(v[it].z) << 32)
              | ((unsigned long long)f2bf(v[it].w) << 48);
            *(unsigned long long*)(&afrag_lds[g][0] + kc * 512 + gp * 8 + j) = pk;
        }
    }
    __syncthreads();

    const int wave = tid >> 6;
    const int lane = tid & 63;
    const int t0   = wave * 2;
    const int rr_l = lane & 15;
    const int q_l  = lane >> 4;
    const int g_e  = q_l * 16 + (rr_l ^ q_l);        // even kc granule
    const int g_o  = q_l * 16 + (rr_l ^ q_l ^ 4);    // odd kc granule

    fx4 acc00 = (fx4){0.f, 0.f, 0.f, 0.f};
    fx4 acc01 = (fx4){0.f, 0.f, 0.f, 0.f};
    fx4 acc10 = (fx4){0.f, 0.f, 0.f, 0.f};
    fx4 acc11 = (fx4){0.f, 0.f, 0.f, 0.f};

    const bf16x8* a0p = (const bf16x8*)&afrag_lds[0][0];
    const bf16x8* a1p = (const bf16x8*)&afrag_lds[1][0];
    const bf16x8* wfp = (const bf16x8*)wf + t0 * 64 + lane;

#pragma unroll 4
    for (int kc = 0; kc < 16; kc++) {
        int gidx = (kc & 1) ? g_o : g_e;
        bf16x8 a0 = a0p[kc * 64 + gidx];
        bf16x8 a1 = a1p[kc * 64 + gidx];
        bf16x8 b0 = wfp[kc * 512];
        bf16x8 b1 = wfp[kc * 512 + 64];
        acc00 = __builtin_amdgcn_mfma_f32_16x16x32_bf16(a0, b0, acc00, 0, 0, 0);
        acc01 = __builtin_amdgcn_mfma_f32_16x16x32_bf16(a0, b1, acc01, 0, 0, 0);
        acc10 = __builtin_amdgcn_mfma_f32_16x16x32_bf16(a1, b0, acc10, 0, 0, 0);
        acc11 = __builtin_amdgcn_mfma_f32_16x16x32_bf16(a1, b1, acc11, 0, 0, 0);
    }

    // ---- epilogue: stage 32x128 bf16 tile in LDS, store coalesced dwordx4 ----
    __syncthreads();   // all waves done reading afrag_lds
    unsigned short* orow = (unsigned short*)&afrag_lds[0][0];   // [32][128] shorts = 8KB
    {
        const int q = lane >> 4;
        const int c = lane & 15;
#pragma unroll
        for (int reg = 0; reg < 4; reg++) {
            int r0 = q * 4 + reg;
            orow[r0 * 128 + t0 * 16 + c]              = f2bf(acc00[reg]);
            orow[r0 * 128 + (t0 + 1) * 16 + c]        = f2bf(acc01[reg]);
            orow[(16 + r0) * 128 + t0 * 16 + c]       = f2bf(acc10[reg]);
            orow[(16 + r0) * 128 + (t0 + 1) * 16 + c] = f2bf(acc11[reg]);
        }
    }
    __syncthreads();
    {
        const int4* osrc = (const int4*)&afrag_lds[0][0];
#pragma unroll
        for (int p = 0; p < 2; p++) {
            int idx = tid + p * 256;          // 0..511 int4, 16 per row
            int r   = idx >> 4;
            int gr  = row0 + r;
            if (gr < N_NODES)
                ((int4*)x)[(size_t)gr * 16 + (idx & 15)] = osrc[idx];
        }
    }
}

// ---------------- scan phase A: block-local exclusive scan + out_norm ----------------
__global__ __launch_bounds__(1024) void scan_local(
    const int* __restrict__ in_deg, int* __restrict__ row_ptr, int* __restrict__ bsum,
    const int* __restrict__ out_deg, float* __restrict__ out_norm)
{
    __shared__ int wsum[16];
    const int tid = threadIdx.x;
    const int lane = tid & 63, wave = tid >> 6;
    int i = blockIdx.x * 1024 + tid;
    int v = (i < N_NODES) ? in_deg[i] : 0;
    int sv = v;
#pragma unroll
    for (int off = 1; off < 64; off <<= 1) {
        int t = __shfl_up(sv, off);
        if (lane >= off) sv += t;
    }
    if (lane == 63) wsum[wave] = sv;
    if (i < N_NODES)
        out_norm[i] = rsqrtf(fmaxf((float)out_deg[i], 1.0f));
    __syncthreads();
    if (wave == 0) {
        int wv = (lane < 16) ? wsum[lane] : 0;
#pragma unroll
        for (int off = 1; off < 16; off <<= 1) {
            int t = __shfl_up(wv, off);
            if (lane >= off) wv += t;
        }
        if (lane < 16) wsum[lane] = wv;
    }
    __syncthreads();
    int excl = ((wave > 0) ? wsum[wave - 1] : 0) + (sv - v);
    if (i < N_NODES) row_ptr[i] = excl;
    if (tid == 1023) bsum[blockIdx.x] = wsum[15];
}

// ---------------- scan phase B+C merged: each block re-scans bsums itself ----------------
__global__ __launch_bounds__(1024) void scan_add2(
    int* __restrict__ row_ptr, const int* __restrict__ bsum)
{
    __shared__ int off_s, tot_s;
    const int tid = threadIdx.x;
    if (tid < 64) {
        int v = (tid < NB_SCAN) ? bsum[tid] : 0;
        int sv = v;
#pragma unroll
        for (int off = 1; off < 64; off <<= 1) {
            int t = __shfl_up(sv, off);
            if (tid >= off) sv += t;
        }
        int pre = __shfl(sv, (blockIdx.x == 0) ? 0 : (blockIdx.x - 1));
        int tot = __shfl(sv, NB_SCAN - 1);
        if (tid == 0) {
            off_s = (blockIdx.x == 0) ? 0 : pre;
            tot_s = tot;
        }
    }
    __syncthreads();
    int i = blockIdx.x * 1024 + tid;
    if (i < N_NODES) row_ptr[i] += off_s;
    if (blockIdx.x == 0 && tid == 0) row_ptr[N_NODES] = tot_s;
}

// ---------------- CSR fill (atomic-free) ----------------
__global__ __launch_bounds__(256) void fill_kernel(
    const int* __restrict__ src, const int* __restrict__ dst,
    const int* __restrict__ row_ptr, const int* __restrict__ edge_pos,
    int* __restrict__ csr_src)
{
    int e = blockIdx.x * 256 + threadIdx.x;
    if (e < N_EDGES) {
        int d = dst[e];
        csr_src[row_ptr[d] + edge_pos[e]] = src[e];
    }
}

// ---------------- fused aggregate + norms + bias + LayerNorm ----------------
// one wave per node; quarter-wave (16 lanes) per edge; lane covers 8 feats (uint4).
// per-lane weights prefetched at batch load -> shfl'd, no random load on dep path.
#define ACC4(uu, ww) {                                                    \
    float p0,p1,p2,p3,p4,p5,p6,p7;                                        \
    bf2x(uu.x,p0,p1); bf2x(uu.y,p2,p3);                                   \
    bf2x(uu.z,p4,p5); bf2x(uu.w,p6,p7);                                   \
    a0 += p0*ww; a1 += p1*ww; a2 += p2*ww; a3 += p3*ww;                   \
    a4 += p4*ww; a5 += p5*ww; a6 += p6*ww; a7 += p7*ww; }

__global__ __launch_bounds__(256) void aggregate_kernel(
    const unsigned short* __restrict__ x, const int* __restrict__ row_ptr,
    const int* __restrict__ csr_src, const float* __restrict__ out_norm,
    const float* __restrict__ b, const float* __restrict__ gamma,
    const float* __restrict__ beta, float* __restrict__ out)
{
    const int n    = blockIdx.x * 4 + (threadIdx.x >> 6);
    const int lane = threadIdx.x & 63;
    const int qi   = lane >> 4;          // edge slot within group of 4
    const int c    = lane & 15;          // feat group: 8c..8c+7
    const int start = row_ptr[n];
    const int end   = row_ptr[n + 1];

    float a0 = 0.f, a1 = 0.f, a2 = 0.f, a3 = 0.f;
    float a4 = 0.f, a5 = 0.f, a6 = 0.f, a7 = 0.f;

    for (int base = start; base < end; base += 64) {
        int  me   = base + lane;
        bool vld  = (me < end);
        int  msrc = vld ? csr_src[me] : 0;
        float mw  = vld ? out_norm[msrc] : 0.f;   // off the dependent path
        int cnt = min(64, end - base);
        int ng  = (cnt + 3) >> 2;                  // groups of 4 edges
        int g = 0;
        for (; g + 4 <= ng; g += 4) {
            int i0 = 4 * g + qi, i1 = i0 + 4, i2 = i0 + 8, i3 = i0 + 12;
            int s0 = __shfl(msrc, i0);
            int s1 = __shfl(msrc, i1);
            int s2 = __shfl(msrc, i2);
            int s3 = __shfl(msrc, i3);
            float w0 = __shfl(mw, i0);
            float w1 = __shfl(mw, i1);
            float w2 = __shfl(mw, i2);
            float w3 = __shfl(mw, i3);
            uint4 u0 = *(const uint4*)(x + (size_t)s0 * NHID + c * 8);
            uint4 u1 = *(const uint4*)(x + (size_t)s1 * NHID + c * 8);
            uint4 u2 = *(const uint4*)(x + (size_t)s2 * NHID + c * 8);
            uint4 u3 = *(const uint4*)(x + (size_t)s3 * NHID + c * 8);
            ACC4(u0, w0) ACC4(u1, w1) ACC4(u2, w2) ACC4(u3, w3)
        }
        for (; g < ng; ++g) {
            int i0 = 4 * g + qi;
            int s0 = __shfl(msrc, i0);
            float w0 = __shfl(mw, i0);
            uint4 u0 = *(const uint4*)(x + (size_t)s0 * NHID + c * 8);
            ACC4(u0, w0)
        }
    }

    // combine the 4 quarter-wave groups (all share the same c)
    a0 += __shfl_xor(a0, 16); a0 += __shfl_xor(a0, 32);
    a1 += __shfl_xor(a1, 16); a1 += __shfl_xor(a1, 32);
    a2 += __shfl_xor(a2, 16); a2 += __shfl_xor(a2, 32);
    a3 += __shfl_xor(a3, 16); a3 += __shfl_xor(a3, 32);
    a4 += __shfl_xor(a4, 16); a4 += __shfl_xor(a4, 32);
    a5 += __shfl_xor(a5, 16); a5 += __shfl_xor(a5, 32);
    a6 += __shfl_xor(a6, 16); a6 += __shfl_xor(a6, 32);
    a7 += __shfl_xor(a7, 16); a7 += __shfl_xor(a7, 32);

    float inorm = rsqrtf(fmaxf((float)(end - start), 1.0f));
    float4 b0 = *(const float4*)(b + c * 8);
    float4 b1 = *(const float4*)(b + c * 8 + 4);
    float v0 = a0 * inorm + b0.x;
    float v1 = a1 * inorm + b0.y;
    float v2 = a2 * inorm + b0.z;
    float v3 = a3 * inorm + b0.w;
    float v4 = a4 * inorm + b1.x;
    float v5 = a5 * inorm + b1.y;
    float v6 = a6 * inorm + b1.z;
    float v7 = a7 * inorm + b1.w;

    float s = ((v0 + v1) + (v2 + v3)) + ((v4 + v5) + (v6 + v7));
#pragma unroll
    for (int off = 8; off > 0; off >>= 1) s += __shfl_xor(s, off);
    float mu = s * (1.0f / 128.0f);

    float d0 = v0 - mu, d1 = v1 - mu, d2 = v2 - mu, d3 = v3 - mu;
    float d4 = v4 - mu, d5 = v5 - mu, d6 = v6 - mu, d7 = v7 - mu;
    float qd = ((d0*d0 + d1*d1) + (d2*d2 + d3*d3)) + ((d4*d4 + d5*d5) + (d6*d6 + d7*d7));
#pragma unroll
    for (int off = 8; off > 0; off >>= 1) qd += __shfl_xor(qd, off);
    float var = qd * (1.0f / 128.0f);
    float rs = rsqrtf(var + LN_EPS);

    if (lane < 16) {
        float4 gg = *(const float4*)(gamma + c * 8);
        float4 be = *(const float4*)(beta + c * 8);
        float4 o;
        o.x = d0 * rs * gg.x + be.x;
        o.y = d1 * rs * gg.y + be.y;
        o.z = d2 * rs * gg.z + be.z;
        o.w = d3 * rs * gg.w + be.w;
        *(float4*)(out + (size_t)n * NHID + c * 8) = o;
    } else if (lane < 32) {
        float4 gg = *(const float4*)(gamma + c * 8 + 4);
        float4 be = *(const float4*)(beta + c * 8 + 4);
        float4 o;
        o.x = d4 * rs * gg.x + be.x;
        o.y = d5 * rs * gg.y + be.y;
        o.z = d6 * rs * gg.z + be.z;
        o.w = d7 * rs * gg.w + be.w;
        *(float4*)(out + (size_t)n * NHID + c * 8 + 4) = o;
    }
}

// ---------------- launch ----------------
extern "C" void kernel_launch(void* const* d_in, const int* in_sizes, int n_in,
                              void* d_out, int out_size, void* d_ws, size_t ws_size,
                              hipStream_t stream) {
    const float* h     = (const float*)d_in[0];
    const int*   src   = (const int*)d_in[1];
    const int*   dst   = (const int*)d_in[2];
    const float* W     = (const float*)d_in[3];
    const float* b     = (const float*)d_in[4];
    const float* gamma = (const float*)d_in[5];
    const float* beta  = (const float*)d_in[6];
    float* out = (float*)d_out;

    char* ws = (char*)d_ws;
    const size_t DEG_BYTES = 200704;   // 50000*4 padded
    const size_t RP_BYTES  = 200960;   // 50001*4 padded
    int*            out_deg  = (int*)(ws);
    int*            in_deg   = (int*)(ws + DEG_BYTES);
    int*            row_ptr  = (int*)(ws + 2 * DEG_BYTES);
    float*          out_norm = (float*)(ws + 2 * DEG_BYTES + RP_BYTES);
    int*            bsum     = (int*)(ws + 3 * DEG_BYTES + RP_BYTES);
    int*            edge_pos = (int*)(ws + 3 * DEG_BYTES + RP_BYTES + 1024);
    int*            csr_src  = (int*)(ws + 3 * DEG_BYTES + RP_BYTES + 1024 + (size_t)N_EDGES * 4);
    unsigned short* wf       = (unsigned short*)(ws + 3 * DEG_BYTES + RP_BYTES + 1024 + 2 * (size_t)N_EDGES * 4);
    unsigned short* x        = (unsigned short*)(ws + 3 * DEG_BYTES + RP_BYTES + 1024 + 2 * (size_t)N_EDGES * 4 + 131072);

    prep_kernel<<<64, 256, 0, stream>>>(W, wf, (int4*)ws);
    fused_gemm_degree<<<GEMM_BLOCKS + DEG_BLOCKS, 256, 0, stream>>>(
        h, wf, x, src, dst, out_deg, in_deg, edge_pos);
    scan_local<<<NB_SCAN, 1024, 0, stream>>>(in_deg, row_ptr, bsum, out_deg, out_norm);
    scan_add2 <<<NB_SCAN, 1024, 0, stream>>>(row_ptr, bsum);
    fill_kernel<<<(N_EDGES + 255) / 256, 256, 0, stream>>>(src, dst, row_ptr, edge_pos, csr_src);
    aggregate_kernel<<<N_NODES / 4, 256, 0, stream>>>(
        x, row_ptr, csr_src, out_norm, b, gamma, beta, out);
}